// Round 4
// baseline (40.969 us; speedup 1.0000x reference)
//
#include <hip/hip_runtime.h>

#define B_  256
#define P_  1152
#define J_  10
#define NT  1024
#define NW  16
#define LOG2E 1.44269504088896340736f

// Rank-8 routing (b[p,j] == x[p].Z[j]) + fully fused e-computation:
// per iteration just TWO phases:
//   Y: for each p-group, b = x.Z via 3-level kk-group shfl reduce,
//      e = exp2(b) in-register, y[j][k] += e*x[k], S[j] += e (mask-fma)
//   mega: s = W.y/S -> squash -> v -> z -> Z += z*log2e  (160 threads)
// No et array, no S-pass, 6 barriers total.
//
// LDS floats (13328 = 53312 B):
//  xs    [1152][9] @0      stride-9 rows (max 2-way bank aliasing = free)
//  Wl    [10][16][9] @10368
//  ypart [16][80]  @11808
//  spart [16][10]  @13088
//  Zacc  [80]      @13248

__global__ __launch_bounds__(NT, 4) void caps_kernel(const float* __restrict__ x,
                                                     const float* __restrict__ Wg,
                                                     float* __restrict__ out) {
  extern __shared__ float sm[];
  float* xs    = sm;
  float* Wl    = sm + 10368;
  float* ypart = sm + 11808;
  float* spart = sm + 13088;
  float* Zacc  = sm + 13248;

  const int tid  = threadIdx.x;
  const int w    = tid >> 6;
  const int lane = tid & 63;
  const int b    = blockIdx.x;
  const int psub = lane >> 3, kk = lane & 7;

  // ---------------- preamble: stage x, W ----------------
  const float* xb = x + (size_t)b * (P_ * 8);
  for (int i = tid; i < (P_ * 8) / 4; i += NT) {
    float4 v4 = reinterpret_cast<const float4*>(xb)[i];
    int p = i >> 1, k0 = (i & 1) * 4;
    float* dst = xs + p * 9 + k0;
    dst[0] = v4.x; dst[1] = v4.y; dst[2] = v4.z; dst[3] = v4.w;
  }
  for (int i = tid; i < J_ * 16 * 8; i += NT) Wl[(i >> 3) * 9 + (i & 7)] = Wg[i];
  __syncthreads();

  for (int it = 0; it < 3; ++it) {
    // ---- fused Y-pass: y[j][k] = sum_p exp2(x[p].Z[j]) x[p][k] ----
    if (it == 0) {                         // e == 1: plain column sum
      float a0 = 0.f;
      #pragma unroll
      for (int c = w; c < 144; c += NW) a0 += xs[(c * 8 + psub) * 9 + kk];
      a0 += __shfl_xor(a0, 8); a0 += __shfl_xor(a0, 16); a0 += __shfl_xor(a0, 32);
      if (lane < 8) {
        #pragma unroll
        for (int j = 0; j < J_; ++j) ypart[w * 80 + j * 8 + lane] = a0;
      }
    } else {
      float Zr[J_];
      #pragma unroll
      for (int j = 0; j < J_; ++j) Zr[j] = Zacc[j * 8 + kk];
      const float msk = (kk == 0) ? 1.0f : 0.0f;
      float acc[J_], accs[J_];
      #pragma unroll
      for (int j = 0; j < J_; ++j) { acc[j] = 0.f; accs[j] = 0.f; }
      #pragma unroll
      for (int c = w; c < 144; c += NW) {
        const float xv = xs[(c * 8 + psub) * 9 + kk];
        #pragma unroll
        for (int j = 0; j < J_; ++j) {
          float t = xv * Zr[j];            // b[p][j] via kk-group butterfly
          t += __shfl_xor(t, 1);
          t += __shfl_xor(t, 2);
          t += __shfl_xor(t, 4);
          const float e = exp2f(t);        // replicated across the 8-lane group
          acc[j]  = fmaf(e, xv,  acc[j]);
          accs[j] = fmaf(e, msk, accs[j]);
        }
      }
      #pragma unroll
      for (int j = 0; j < J_; ++j) {       // reduce over psub (lane bits 3..5)
        acc[j]  += __shfl_xor(acc[j], 8);
        acc[j]  += __shfl_xor(acc[j], 16);
        acc[j]  += __shfl_xor(acc[j], 32);
        accs[j] += __shfl_xor(accs[j], 8);
        accs[j] += __shfl_xor(accs[j], 16);
        accs[j] += __shfl_xor(accs[j], 32);
      }
      if (lane == 0) {
        #pragma unroll
        for (int j = 0; j < J_; ++j) spart[w * 10 + j] = accs[j];
      }
      if (lane < 8) {
        #pragma unroll
        for (int j = 0; j < J_; ++j) ypart[w * 80 + j * 8 + lane] = acc[j];
      }
    }
    __syncthreads();

    // ---- mega (tid<160): combine -> s -> squash -> v (-> out | Z update) ----
    if (tid < 160) {
      const int j = tid >> 4, d = tid & 15;
      float ys = 0.f;
      if (d < 8) {
        #pragma unroll
        for (int w2 = 0; w2 < NW; ++w2) ys += ypart[w2 * 80 + j * 8 + d];
      }
      float Ssum;
      if (it == 0) {
        Ssum = (float)P_;
      } else {
        float sp = spart[d * 10 + j];      // d indexes the wave partial
        sp += __shfl_xor(sp, 1); sp += __shfl_xor(sp, 2);
        sp += __shfl_xor(sp, 4); sp += __shfl_xor(sp, 8);
        Ssum = sp;
      }
      float wk[8];
      #pragma unroll
      for (int k = 0; k < 8; ++k) wk[k] = Wl[(j * 16 + d) * 9 + k];
      float s = 0.f;
      #pragma unroll
      for (int k = 0; k < 8; ++k)
        s = fmaf(wk[k], __shfl(ys, (j & 3) * 16 + k), s);
      s /= Ssum;
      float sq = s * s;                    // squash via 16-lane group reduce
      sq += __shfl_xor(sq, 1); sq += __shfl_xor(sq, 2);
      sq += __shfl_xor(sq, 4); sq += __shfl_xor(sq, 8);
      const float scal = sq / ((1.0f + sq) * sqrtf(sq + 1e-9f));
      const float v = s * scal;
      if (it == 2) {
        out[b * 160 + tid] = v;
      } else {                             // z[j][k] = sum_d W[j][d][k] v_d
        float zmine = 0.f;
        #pragma unroll
        for (int k = 0; k < 8; ++k) {
          float t = wk[k] * v;
          t += __shfl_xor(t, 1); t += __shfl_xor(t, 2);
          t += __shfl_xor(t, 4); t += __shfl_xor(t, 8);
          if (d == k) zmine = t;
        }
        if (d < 8)                          // pre-scaled so Y-pass uses exp2
          Zacc[j * 8 + d] = (it == 0) ? zmine * LOG2E
                                      : fmaf(zmine, LOG2E, Zacc[j * 8 + d]);
      }
    }
    if (it < 2) __syncthreads();
  }
}

extern "C" void kernel_launch(void* const* d_in, const int* in_sizes, int n_in,
                              void* d_out, int out_size, void* d_ws, size_t ws_size,
                              hipStream_t stream) {
  (void)in_sizes; (void)n_in; (void)out_size; (void)d_ws; (void)ws_size;
  const float* x = (const float*)d_in[0];
  const float* W = (const float*)d_in[1];
  float* out = (float*)d_out;

  const size_t smem = 13328u * sizeof(float);  // 53312 B
  (void)hipFuncSetAttribute(reinterpret_cast<const void*>(caps_kernel),
                            hipFuncAttributeMaxDynamicSharedMemorySize, (int)smem);
  caps_kernel<<<B_, NT, smem, stream>>>(x, W, out);
}

// Round 5
// 17.906 us; speedup vs baseline: 2.2880x; 2.2880x over previous
//
#include <hip/hip_runtime.h>

#define B_   256
#define P_   1152
#define J_   10
#define NT   384      // 6 waves
#define NWAVE 6
#define ROWS 3        // p-rows per lane: p = w*192 + r*64 + lane
#define LOG2E 1.44269504088896340736f

// ---- DPP helpers (VALU-pipe cross-lane, no LDS) ----
template<int CTRL>
__device__ __forceinline__ float dpp_mov(float v) {
  int r = __builtin_amdgcn_update_dpp(0, __builtin_bit_cast(int, v), CTRL, 0xF, 0xF, true);
  return __builtin_bit_cast(float, r);
}
// row_shr:N = 0x110|N ; after 1,2,4,8 lane15 of each 16-row holds the row sum
__device__ __forceinline__ float rowsum16(float v) {
  v += dpp_mov<0x111>(v);
  v += dpp_mov<0x112>(v);
  v += dpp_mov<0x114>(v);
  v += dpp_mov<0x118>(v);
  return v;
}

// LDS (static, 16.3 KB):
//  ypart [24][96]  per-16-lane-row partials: cols 0..79 = acc[j][k] at j*8+k,
//                  cols 80..89 = accs[j] (e-sums), 90..91 pad
//  Wt    [80][18]  W transposed: Wt[(j*8+k)*18 + d] = W[j][d][k]
//  red   [92]      reduced ysum[0..79] + Ssum[80..89]
//  vv    [160]     v[j][d]
//  Zacc  [80]      cumulative z * log2(e)
__global__ __launch_bounds__(NT, 2) void caps_kernel(const float* __restrict__ x,
                                                     const float* __restrict__ Wg,
                                                     float* __restrict__ out) {
  __shared__ float ypart[24 * 96];
  __shared__ float Wt[80 * 18];
  __shared__ float red[92];
  __shared__ float vv[160];
  __shared__ float Zacc[80];

  const int tid  = threadIdx.x;
  const int w    = tid >> 6;
  const int lane = tid & 63;
  const int b    = blockIdx.x;

  // ---- preamble: x rows -> registers (never touches LDS), W -> Wt ----
  float xr[ROWS][8];
  {
    const float* xb = x + ((size_t)b * P_ + w * 192 + lane) * 8;
    #pragma unroll
    for (int r = 0; r < ROWS; ++r) {
      const float4 a = *reinterpret_cast<const float4*>(xb + r * 64 * 8);
      const float4 c = *reinterpret_cast<const float4*>(xb + r * 64 * 8 + 4);
      xr[r][0] = a.x; xr[r][1] = a.y; xr[r][2] = a.z; xr[r][3] = a.w;
      xr[r][4] = c.x; xr[r][5] = c.y; xr[r][6] = c.z; xr[r][7] = c.w;
    }
  }
  for (int t = tid; t < J_ * 16 * 8; t += NT) {
    const int j = t >> 7, d = (t >> 3) & 15, k = t & 7;
    Wt[(j * 8 + k) * 18 + d] = Wg[t];
  }
  __syncthreads();

  for (int it = 0; it < 3; ++it) {
    // ---------------- Y phase: all in registers, DPP partial reduce ----------------
    if (it == 0) {                      // e == 1: y[j][k] = colsum(x)[k], S = P
      float cs[8];
      #pragma unroll
      for (int k = 0; k < 8; ++k)
        cs[k] = rowsum16(xr[0][k] + xr[1][k] + xr[2][k]);
      if ((lane & 15) == 15) {
        const int row = w * 4 + (lane >> 4);
        *reinterpret_cast<float4*>(&ypart[row * 96 + 0]) = make_float4(cs[0], cs[1], cs[2], cs[3]);
        *reinterpret_cast<float4*>(&ypart[row * 96 + 4]) = make_float4(cs[4], cs[5], cs[6], cs[7]);
      }
    } else {
      float Zr[J_][8];
      #pragma unroll
      for (int j = 0; j < J_; ++j) {    // broadcast b128 reads
        const float4 a = *reinterpret_cast<const float4*>(&Zacc[j * 8]);
        const float4 c = *reinterpret_cast<const float4*>(&Zacc[j * 8 + 4]);
        Zr[j][0] = a.x; Zr[j][1] = a.y; Zr[j][2] = a.z; Zr[j][3] = a.w;
        Zr[j][4] = c.x; Zr[j][5] = c.y; Zr[j][6] = c.z; Zr[j][7] = c.w;
      }
      float acc[J_][8], accs[J_];
      #pragma unroll
      for (int j = 0; j < J_; ++j) {
        accs[j] = 0.f;
        #pragma unroll
        for (int k = 0; k < 8; ++k) acc[j][k] = 0.f;
      }
      #pragma unroll
      for (int r = 0; r < ROWS; ++r) {
        #pragma unroll
        for (int j = 0; j < J_; ++j) {
          float t = xr[r][0] * Zr[j][0];
          #pragma unroll
          for (int k = 1; k < 8; ++k) t = fmaf(xr[r][k], Zr[j][k], t);
          const float e = exp2f(t);     // Zacc is pre-scaled by log2(e)
          accs[j] += e;
          #pragma unroll
          for (int k = 0; k < 8; ++k) acc[j][k] = fmaf(e, xr[r][k], acc[j][k]);
        }
      }
      #pragma unroll
      for (int j = 0; j < J_; ++j) {    // DPP reduce: VALU pipe only
        #pragma unroll
        for (int k = 0; k < 8; ++k) acc[j][k] = rowsum16(acc[j][k]);
        accs[j] = rowsum16(accs[j]);
      }
      if ((lane & 15) == 15) {
        const int row = w * 4 + (lane >> 4);
        float* rp = &ypart[row * 96];
        #pragma unroll
        for (int j = 0; j < J_; ++j) {
          *reinterpret_cast<float4*>(rp + j * 8)     = make_float4(acc[j][0], acc[j][1], acc[j][2], acc[j][3]);
          *reinterpret_cast<float4*>(rp + j * 8 + 4) = make_float4(acc[j][4], acc[j][5], acc[j][6], acc[j][7]);
        }
        *reinterpret_cast<float4*>(rp + 80) = make_float4(accs[0], accs[1], accs[2], accs[3]);
        *reinterpret_cast<float4*>(rp + 84) = make_float4(accs[4], accs[5], accs[6], accs[7]);
        *reinterpret_cast<float4*>(rp + 88) = make_float4(accs[8], accs[9], 0.f, 0.f);
      }
    }
    __syncthreads();

    // ---------------- M_A: combine 24 row-partials ----------------
    if (tid < ((it == 0) ? 8 : 90)) {
      float s = 0.f;
      #pragma unroll
      for (int r = 0; r < 24; ++r) s += ypart[r * 96 + tid];
      red[tid] = s;
    }
    __syncthreads();

    // ---------------- M_B: s -> squash -> v ----------------
    if (tid < 160) {
      const int j = tid >> 4, d = tid & 15;
      const int yb = (it == 0) ? 0 : j * 8;
      const float Ss = (it == 0) ? (float)P_ : red[80 + j];
      float s = 0.f;
      #pragma unroll
      for (int k = 0; k < 8; ++k)
        s = fmaf(Wt[(j * 8 + k) * 18 + d], red[yb + k], s);
      s /= Ss;
      float sq = s * s;
      sq += __shfl_xor(sq, 1); sq += __shfl_xor(sq, 2);
      sq += __shfl_xor(sq, 4); sq += __shfl_xor(sq, 8);
      const float scal = sq / ((1.0f + sq) * sqrtf(sq + 1e-9f));
      const float v = s * scal;
      if (it == 2) out[b * 160 + tid] = v;
      else         vv[tid] = v;
    }
    if (it == 2) break;
    __syncthreads();

    // ---------------- M_C: z[j][k] = sum_d W[j][d][k] v[j][d]; Zacc += z*log2e ----------------
    if (tid < 80) {
      const int j = tid >> 3, k = tid & 7;
      float z = 0.f;
      #pragma unroll
      for (int d = 0; d < 16; ++d)
        z = fmaf(Wt[tid * 18 + d], vv[j * 16 + d], z);
      Zacc[tid] = (it == 0) ? z * LOG2E : fmaf(z, LOG2E, Zacc[tid]);
    }
    __syncthreads();
  }
}

extern "C" void kernel_launch(void* const* d_in, const int* in_sizes, int n_in,
                              void* d_out, int out_size, void* d_ws, size_t ws_size,
                              hipStream_t stream) {
  (void)in_sizes; (void)n_in; (void)out_size; (void)d_ws; (void)ws_size;
  const float* x = (const float*)d_in[0];
  const float* W = (const float*)d_in[1];
  float* out = (float*)d_out;
  caps_kernel<<<B_, NT, 0, stream>>>(x, W, out);
}